// Round 10
// baseline (277.578 us; speedup 1.0000x reference)
//
#include <hip/hip_runtime.h>

#define B_N 1024
#define X_N 1024
#define Y_N 16384
#define Z_N 1000
#define KD  1024
#define MARGIN 0.004f

// output float offsets
#define OFF_ACT      0
#define OFF_MAXRESP  1
#define OFF_WX       1025
#define OFF_WZ       16778241
#define OFF_U        33162241
#define OFF_THR      49546241
#define OFF_AGE      49562625
#define OFF_ZAGE     49579009

// scratch in not-yet-written d_out regions (16B-aligned byte offsets)
#define SCR_B_BYTES    4112ull       /* Bb f16 32MB, in OFF_WX region */
#define SCR_S_BYTES    67112976ull   /* Sc f16 32MB, in OFF_WZ region */
#define SCR_A_BYTES    132648976ull  /* Ab f16 2MB, in OFF_U region */
#define SCR_CAND_BYTES 134746128ull  /* u32[1024][512] = 2MB, in OFF_U region */
#define SCR_WZT_BYTES  136843280ull  /* wzt f16 [1024 z-slots][Y_N] 32MB, in OFF_U region */

// ws float offsets
#define WS_INV_X    0
#define WS_INV_WX   1024
#define WS_INV_WZ   17408
#define WS_FIDX     38912   /* int[1024] */
#define WS_CNT      39936   /* int[16384] */
#define WS_ZCNT     56320   /* int[1024] */
#define WS_SEGMIN   57344   /* uint[16384] */
#define WS_CTR      73728   /* int[8]: [0]=unact_cnt [1]=act_cnt [2]=min_act_idx */
#define WS_MBITS    73736   /* u64[256] */
#define WS_CCNT     74248   /* int[1024] */

typedef unsigned short ushort_t;
typedef _Float16 f16x8 __attribute__((ext_vector_type(8)));
typedef float f32x4 __attribute__((ext_vector_type(4)));

__device__ __forceinline__ unsigned enc_f(float f) {
    unsigned u = __float_as_uint(f);
    return (u & 0x80000000u) ? ~u : (u | 0x80000000u);
}
__device__ __forceinline__ float dec_f(unsigned e) {
    unsigned u = (e & 0x80000000u) ? (e ^ 0x80000000u) : ~e;
    return __uint_as_float(u);
}
__device__ __forceinline__ unsigned long long pack_vi(float v, int y) {
    return ((unsigned long long)enc_f(v) << 32) |
           (unsigned long long)(0xFFFFFFFFu - (unsigned)y);
}
__device__ __forceinline__ ushort_t f2h(float f) {
    _Float16 h = (_Float16)f;           // RTNE
    ushort_t u; __builtin_memcpy(&u, &h, 2); return u;
}
__device__ __forceinline__ float h2f(unsigned lo16) {
    ushort_t u = (ushort_t)lo16; _Float16 h;
    __builtin_memcpy(&h, &u, 2); return (float)h;
}

#define GLOAD16(gp, lp) __builtin_amdgcn_global_load_lds( \
    (const __attribute__((address_space(1))) void*)(gp),  \
    (__attribute__((address_space(3))) void*)(lp), 16, 0, 0)

__global__ void init_kernel(int* cnt, unsigned* segmin, int* zcnt, int* ctr) {
    int i = blockIdx.x * 256 + threadIdx.x;
    if (i < Y_N) { cnt[i] = 0; segmin[i] = 0xFFFFFFFFu; }
    if (i < 1024) zcnt[i] = 0;
    if (i < 8) ctr[i] = (i == 2) ? 0x7FFFFFFF : 0;
}

__global__ void unact_kernel(const float* __restrict__ y_age, int* ctr,
                             unsigned long long* __restrict__ mbits) {
    int i = blockIdx.x * 256 + threadIdx.x;
    int a = (y_age[i] < 1.0f) ? 1 : 0;
    unsigned long long m = __ballot(a);
    int mi = a ? 0x7FFFFFFF : i;   // min index over ACTIVATED neurons
    #pragma unroll
    for (int s = 32; s > 0; s >>= 1) mi = min(mi, __shfl_xor(mi, s, 64));
    if ((threadIdx.x & 63) == 0) {
        atomicAdd(ctr, (int)__popcll(m));
        mbits[i >> 6] = m;
        if (mi != 0x7FFFFFFF) atomicMin(&ctr[2], mi);
    }
}

// fused: row-norm of x + pack A row [B_N][KD] f16 = x_hat (one block per b)
__global__ __launch_bounds__(256) void pack_x_kernel(
    const float* __restrict__ x, ushort_t* __restrict__ A, float* __restrict__ inv_x) {
    const int b = blockIdx.x, t = threadIdx.x;
    const int lane = t & 63, wid = t >> 6;
    float4 v = reinterpret_cast<const float4*>(x + (size_t)b * X_N)[t];
    float ss = v.x*v.x + v.y*v.y + v.z*v.z + v.w*v.w;
    #pragma unroll
    for (int s = 32; s > 0; s >>= 1) ss += __shfl_xor(ss, s, 64);
    __shared__ float red[4];
    if (lane == 0) red[wid] = ss;
    __syncthreads();
    float inv = 1.0f / fmaxf(sqrtf(red[0] + red[1] + red[2] + red[3]), 1e-12f);
    if (t == 0) inv_x[b] = inv;
    ushort_t o1[4] = { f2h(v.x*inv), f2h(v.y*inv), f2h(v.z*inv), f2h(v.w*inv) };
    *reinterpret_cast<uint2*>(A + (size_t)b * KD + t * 4) = *reinterpret_cast<uint2*>(o1);
}

// fused: row-norm of wxw + pack B row [Y_N][KD] f16 = wx_hat (one block per y)
__global__ __launch_bounds__(256) void pack_w_kernel(
    const float* __restrict__ wxw, ushort_t* __restrict__ Bm, float* __restrict__ inv_wx) {
    const int y = blockIdx.x, t = threadIdx.x;
    const int lane = t & 63, wid = t >> 6;
    float4 a = reinterpret_cast<const float4*>(wxw + (size_t)y * X_N)[t];
    float s1 = a.x*a.x + a.y*a.y + a.z*a.z + a.w*a.w;
    #pragma unroll
    for (int s = 32; s > 0; s >>= 1) s1 += __shfl_xor(s1, s, 64);
    __shared__ float r1[4];
    if (lane == 0) r1[wid] = s1;
    __syncthreads();
    float inv1 = 1.0f / fmaxf(sqrtf(r1[0] + r1[1] + r1[2] + r1[3]), 1e-12f);
    ushort_t o1[4] = { f2h(a.x*inv1), f2h(a.y*inv1), f2h(a.z*inv1), f2h(a.w*inv1) };
    *reinterpret_cast<uint2*>(Bm + (size_t)y * KD + t * 4) = *reinterpret_cast<uint2*>(o1);
    if (t == 0) inv_wx[y] = inv1;
}

// fused: row-norm of wzw + scaled transpose, ONE read of wzw.
// block handles 64 y-rows; wzt[z][y] = 0.5 * inv_wz[y] * wzw[y][z]  (f16)
__global__ __launch_bounds__(256) void wz_prep_kernel(
    const float* __restrict__ wzw, ushort_t* __restrict__ wzt,
    float* __restrict__ inv_wz) {
    const int y0 = blockIdx.x * 64;
    const int t = threadIdx.x;
    __shared__ ushort_t raw[64][1028];   // stride 2056B: 8B-aligned rows, 4-way bank alias
    __shared__ float ssq[64];
    __shared__ float sinv[64];
    if (t < 64) ssq[t] = 0.f;
    __syncthreads();

    // load + convert + partial ssq (LDS atomics over 64 addresses)
    for (int idx = t; idx < 64 * 250; idx += 256) {
        int row = idx / 250, c4 = idx % 250;
        float4 v = *reinterpret_cast<const float4*>(wzw + (size_t)(y0 + row) * Z_N + c4 * 4);
        ushort_t o[4] = { f2h(v.x), f2h(v.y), f2h(v.z), f2h(v.w) };
        *reinterpret_cast<uint2*>(&raw[row][c4 * 4]) = *reinterpret_cast<uint2*>(o);
        atomicAdd(&ssq[row], v.x*v.x + v.y*v.y + v.z*v.z + v.w*v.w);
    }
    __syncthreads();
    if (t < 64) {
        float inv = 1.0f / fmaxf(sqrtf(ssq[t]), 1e-12f);
        inv_wz[y0 + t] = inv;
        sinv[t] = 0.5f * inv;
    }
    __syncthreads();

    // transposed scaled write: z = p*16 + (t>>4), y = (t&15)*4
    const int yl = (t & 15) * 4;
    float s0 = sinv[yl + 0], s1 = sinv[yl + 1], s2 = sinv[yl + 2], s3 = sinv[yl + 3];
    #pragma unroll 4
    for (int p = 0; p < 64; ++p) {
        int z = p * 16 + (t >> 4);
        if (z < Z_N) {
            ushort_t o[4] = { f2h(h2f(raw[yl + 0][z]) * s0),
                              f2h(h2f(raw[yl + 1][z]) * s1),
                              f2h(h2f(raw[yl + 2][z]) * s2),
                              f2h(h2f(raw[yl + 3][z]) * s3) };
            *reinterpret_cast<uint2*>(wzt + (size_t)z * Y_N + y0 + yl) =
                *reinterpret_cast<uint2*>(o);
        }
    }
}

// f16 MFMA GEMM, 256x256 tile, K=1024, BK=32, 4-buffer 3-deep counted-vmcnt pipeline
__global__ __launch_bounds__(512, 1) void mm256_kernel(const ushort_t* __restrict__ A,
                                                       const ushort_t* __restrict__ Bm,
                                                       ushort_t* __restrict__ S) {
    __shared__ __align__(16) _Float16 lds[4][2][1024][8];
    const int t = threadIdx.x;
    const int wid = t >> 6, lane = t & 63;
    const int bid = blockIdx.x;
    const int lb = (bid & 7) * 32 + (bid >> 3);   // bijective: 256 % 8 == 0
    const int mt = lb & 3, nt = lb >> 2;
    const int b0 = mt * 256, y0 = nt * 256;
    const int wr = wid >> 2, wc = wid & 3;        // 2 x 4 waves
    const int r = lane & 15, gq = lane >> 4;
    const int NK = KD / 32;                        // 32 K-tiles

    f32x4 acc[8][4];
    #pragma unroll
    for (int i = 0; i < 8; ++i)
        #pragma unroll
        for (int j = 0; j < 4; ++j) acc[i][j] = (f32x4){0.f, 0.f, 0.f, 0.f};

    auto stage = [&](int buf, int k0) {
        #pragma unroll
        for (int rr = 0; rr < 2; ++rr) {
            int s = rr * 512 + t;
            int row = s & 255, g = s >> 8;     // g in [0,4)
            GLOAD16(A  + (size_t)(b0 + row) * KD + k0 + g * 8, &lds[buf][0][s][0]);
            GLOAD16(Bm + (size_t)(y0 + row) * KD + k0 + g * 8, &lds[buf][1][s][0]);
        }
    };

    stage(0, 0);
    stage(1, 32);
    stage(2, 64);
    asm volatile("s_waitcnt vmcnt(8)" ::: "memory");
    __builtin_amdgcn_s_barrier();
    asm volatile("" ::: "memory");

    for (int ks = 0; ks < NK; ++ks) {
        const int cur = ks & 3;
        f16x8 bF[4];
        #pragma unroll
        for (int nf = 0; nf < 4; ++nf)
            bF[nf] = *reinterpret_cast<const f16x8*>(
                &lds[cur][1][gq * 256 + wc * 64 + nf * 16 + r][0]);
        __builtin_amdgcn_s_setprio(1);
        #pragma unroll
        for (int mf = 0; mf < 8; ++mf) {
            f16x8 aF = *reinterpret_cast<const f16x8*>(
                &lds[cur][0][gq * 256 + wr * 128 + mf * 16 + r][0]);
            #pragma unroll
            for (int nf = 0; nf < 4; ++nf)
                acc[mf][nf] = __builtin_amdgcn_mfma_f32_16x16x32_f16(
                    aF, bF[nf], acc[mf][nf], 0, 0, 0);
        }
        __builtin_amdgcn_s_setprio(0);
        if (ks == NK - 1) break;

        __builtin_amdgcn_s_barrier();            // all waves done reading buf[cur]
        asm volatile("" ::: "memory");
        if (ks + 3 < NK) {
            stage((ks + 3) & 3, (ks + 3) * 32);
            asm volatile("s_waitcnt vmcnt(8)" ::: "memory");  // tile ks+1 landed
        } else if (ks + 3 == NK) {
            asm volatile("s_waitcnt vmcnt(4)" ::: "memory");
        } else {
            asm volatile("s_waitcnt vmcnt(0)" ::: "memory");
        }
        __builtin_amdgcn_s_barrier();
        asm volatile("" ::: "memory");
    }

    // C layout: col = lane&15, row = (lane>>4)*4 + reg; store 0.5*dot (x-part)
    #pragma unroll
    for (int mf = 0; mf < 8; ++mf) {
        int bg = b0 + wr * 128 + mf * 16 + gq * 4;
        #pragma unroll
        for (int nf = 0; nf < 4; ++nf) {
            int yg = y0 + wc * 64 + nf * 16 + r;
            f32x4 c = acc[mf][nf];
            #pragma unroll
            for (int q = 0; q < 4; ++q)
                S[(size_t)(bg + q) * Y_N + yg] = f2h(0.5f * c[q]);
        }
    }
}

// per-row single-pass: v = score_x + wzt[zb][y] cached in LDS; max + candidates
__global__ __launch_bounds__(256) void scan_kernel(
    const ushort_t* __restrict__ scores, const ushort_t* __restrict__ wzt,
    const int* __restrict__ zlab, const unsigned long long* __restrict__ mbits,
    const int* __restrict__ ctr, unsigned* __restrict__ gcand, int* __restrict__ ccnt) {
    const int b = blockIdx.x, t = threadIdx.x;
    const int lane = t & 63, wid = t >> 6;
    const uint4* srow = reinterpret_cast<const uint4*>(scores + (size_t)b * Y_N);
    const uint4* wrow = reinterpret_cast<const uint4*>(wzt + (size_t)zlab[b] * Y_N);

    __shared__ unsigned vbuf[Y_N / 2];   // 32KB: v as f16 pairs
    __shared__ float rv[4], rm[4];
    __shared__ int nA_s, nB_s;
    __shared__ int cA[256], cB[256];

    float vmax = -1e30f, mmax = -1e30f;
    for (int c = t; c < Y_N / 8; c += 256) {
        uint4 pk = srow[c];
        uint4 wz = wrow[c];
        int yb = c * 8;
        unsigned m8 = (unsigned)((mbits[yb >> 6] >> (yb & 63)) & 0xFFull);
        unsigned w[4] = {pk.x, pk.y, pk.z, pk.w};
        unsigned q[4] = {wz.x, wz.y, wz.z, wz.w};
        #pragma unroll
        for (int j = 0; j < 4; ++j) {
            float v0 = h2f(w[j] & 0xFFFFu) + h2f(q[j] & 0xFFFFu);
            float v1 = h2f(w[j] >> 16) + h2f(q[j] >> 16);
            vmax = fmaxf(vmax, fmaxf(v0, v1));
            mmax = fmaxf(mmax, v0 * (float)((m8 >> (2 * j)) & 1u));
            mmax = fmaxf(mmax, v1 * (float)((m8 >> (2 * j + 1)) & 1u));
            vbuf[c * 4 + j] = (unsigned)f2h(v0) | ((unsigned)f2h(v1) << 16);
        }
    }
    #pragma unroll
    for (int s = 32; s > 0; s >>= 1) {
        vmax = fmaxf(vmax, __shfl_xor(vmax, s, 64));
        mmax = fmaxf(mmax, __shfl_xor(mmax, s, 64));
    }
    if (lane == 0) { rv[wid] = vmax; rm[wid] = mmax; }
    if (t == 0) { nA_s = 0; nB_s = 0; }
    __syncthreads();
    float tA = fmaxf(fmaxf(rv[0], rv[1]), fmaxf(rv[2], rv[3])) - MARGIN;
    float tB = fmaxf(fmaxf(rm[0], rm[1]), fmaxf(rm[2], rm[3])) - MARGIN;
    bool anyu = ctr[0] > 0;

    for (int c = t; c < Y_N / 8; c += 256) {
        int yb = c * 8;
        unsigned m8 = (unsigned)((mbits[yb >> 6] >> (yb & 63)) & 0xFFull);
        #pragma unroll
        for (int jj = 0; jj < 4; ++jj) {
            unsigned pv = vbuf[c * 4 + jj];
            float v0 = h2f(pv & 0xFFFFu);
            float v1 = h2f(pv >> 16);
            if (v0 >= tA) { int p = atomicAdd(&nA_s, 1); if (p < 256) cA[p] = yb + 2*jj; }
            if (v1 >= tA) { int p = atomicAdd(&nA_s, 1); if (p < 256) cA[p] = yb + 2*jj + 1; }
            if (anyu) {
                if (((m8 >> (2*jj)) & 1u) && v0 >= tB) {
                    int p = atomicAdd(&nB_s, 1); if (p < 256) cB[p] = yb + 2*jj;
                }
                if (((m8 >> (2*jj + 1)) & 1u) && v1 >= tB) {
                    int p = atomicAdd(&nB_s, 1); if (p < 256) cB[p] = yb + 2*jj + 1;
                }
            }
        }
    }
    __syncthreads();
    int nA = min(nA_s, 256), nB = min(nB_s, 256);
    unsigned* slab = gcand + (size_t)b * 512;
    for (int i = t; i < nA; i += 256) slab[i] = (unsigned)cA[i];
    for (int i = t; i < nB; i += 256) slab[256 + i] = (unsigned)cB[i];
    if (t == 0) ccnt[b] = nA | (nB << 16);
}

// per-row: exact fp32 rescore (A list, judge, conditional B list) + finalize
__global__ __launch_bounds__(256) void rescore_kernel(
    const unsigned* __restrict__ gcand, const int* __restrict__ ccnt,
    const float* __restrict__ x, const float* __restrict__ inv_x,
    const float* __restrict__ wxw, const float* __restrict__ inv_wx,
    const float* __restrict__ wzw, const float* __restrict__ inv_wz,
    const int* __restrict__ zlab, const float* __restrict__ y_thr,
    const float* __restrict__ y_age, const int* __restrict__ ctr,
    int* final_idx, int* cnt, unsigned* segmin, int* zcnt,
    float* __restrict__ out_maxresp) {
    const int b = blockIdx.x, t = threadIdx.x;
    const int lane = t & 63, wid = t >> 6;
    int pc = ccnt[b];
    int nA = pc & 0xFFFF, nB = pc >> 16;
    int zb = zlab[b];
    float invx = inv_x[b];
    const unsigned* slab = gcand + (size_t)b * 512;

    const float4* xr = reinterpret_cast<const float4*>(x + (size_t)b * X_N);
    float4 xv[4];
    #pragma unroll
    for (int j = 0; j < 4; ++j) xv[j] = xr[j * 64 + lane];

    __shared__ unsigned long long red[4];
    __shared__ unsigned long long sPM;
    __shared__ int sTakeA;

    unsigned long long bA = 0ull;
    for (int c = wid; c < nA; c += 8) {
        int y1 = (int)slab[c];
        int c2 = c + 4;
        bool h2 = c2 < nA;
        int y2 = (int)slab[h2 ? c2 : c];
        const float4* w1 = reinterpret_cast<const float4*>(wxw + (size_t)y1 * X_N);
        const float4* w2 = reinterpret_cast<const float4*>(wxw + (size_t)y2 * X_N);
        float d1 = 0.f, d2 = 0.f;
        #pragma unroll
        for (int j = 0; j < 4; ++j) {
            float4 a1 = w1[j * 64 + lane];
            float4 a2 = w2[j * 64 + lane];
            d1 += xv[j].x*a1.x + xv[j].y*a1.y + xv[j].z*a1.z + xv[j].w*a1.w;
            d2 += xv[j].x*a2.x + xv[j].y*a2.y + xv[j].z*a2.z + xv[j].w*a2.w;
        }
        #pragma unroll
        for (int s = 32; s > 0; s >>= 1) {
            d1 += __shfl_xor(d1, s, 64);
            d2 += __shfl_xor(d2, s, 64);
        }
        float v1 = 0.5f*invx*inv_wx[y1]*d1 + 0.5f*inv_wz[y1]*wzw[(size_t)y1*Z_N + zb];
        unsigned long long p1 = pack_vi(v1, y1);
        bA = (p1 > bA) ? p1 : bA;
        if (h2) {
            float v2 = 0.5f*invx*inv_wx[y2]*d2 + 0.5f*inv_wz[y2]*wzw[(size_t)y2*Z_N + zb];
            unsigned long long p2 = pack_vi(v2, y2);
            bA = (p2 > bA) ? p2 : bA;
        }
    }
    if (lane == 0) red[wid] = bA;
    __syncthreads();
    if (t == 0) {
        unsigned long long pm = red[0];
        #pragma unroll
        for (int j = 1; j < 4; ++j) pm = (red[j] > pm) ? red[j] : pm;
        sPM = pm;
        unsigned enc = (unsigned)(pm >> 32);
        int idx = (int)(0xFFFFFFFFu - (unsigned)(pm & 0xFFFFFFFFull));
        float mresp = dec_f(enc);
        out_maxresp[b] = mresp;
        bool judge = (mresp > y_thr[idx]) || (y_age[idx] < 1.0f);
        bool anyu = ctr[0] > 0;
        sTakeA = (judge || !anyu) ? 1 : 0;
    }
    __syncthreads();

    if (!sTakeA) {
        unsigned long long bB = 0ull;
        for (int c = wid; c < nB; c += 8) {
            int y1 = (int)slab[256 + c];
            int c2 = c + 4;
            bool h2 = c2 < nB;
            int y2 = (int)slab[256 + (h2 ? c2 : c)];
            const float4* w1 = reinterpret_cast<const float4*>(wxw + (size_t)y1 * X_N);
            const float4* w2 = reinterpret_cast<const float4*>(wxw + (size_t)y2 * X_N);
            float d1 = 0.f, d2 = 0.f;
            #pragma unroll
            for (int j = 0; j < 4; ++j) {
                float4 a1 = w1[j * 64 + lane];
                float4 a2 = w2[j * 64 + lane];
                d1 += xv[j].x*a1.x + xv[j].y*a1.y + xv[j].z*a1.z + xv[j].w*a1.w;
                d2 += xv[j].x*a2.x + xv[j].y*a2.y + xv[j].z*a2.z + xv[j].w*a2.w;
            }
            #pragma unroll
            for (int s = 32; s > 0; s >>= 1) {
                d1 += __shfl_xor(d1, s, 64);
                d2 += __shfl_xor(d2, s, 64);
            }
            float v1 = 0.5f*invx*inv_wx[y1]*d1 + 0.5f*inv_wz[y1]*wzw[(size_t)y1*Z_N + zb];
            unsigned long long p1 = pack_vi(v1, y1);
            bB = (p1 > bB) ? p1 : bB;
            if (h2) {
                float v2 = 0.5f*invx*inv_wx[y2]*d2 + 0.5f*inv_wz[y2]*wzw[(size_t)y2*Z_N + zb];
                unsigned long long p2 = pack_vi(v2, y2);
                bB = (p2 > bB) ? p2 : bB;
            }
        }
        if (lane == 0) red[wid] = bB;
    }
    __syncthreads();
    if (t == 0) {
        unsigned long long pm = sPM;
        unsigned enc = (unsigned)(pm >> 32);
        int idx = (int)(0xFFFFFFFFu - (unsigned)(pm & 0xFFFFFFFFull));
        int fin;
        if (sTakeA) {
            fin = idx;
        } else if (nB > 0) {
            unsigned long long pf = red[0];
            #pragma unroll
            for (int j = 1; j < 4; ++j) pf = (red[j] > pf) ? red[j] : pf;
            fin = (int)(0xFFFFFFFFu - (unsigned)(pf & 0xFFFFFFFFull));
        } else {
            fin = ctr[2];
        }
        final_idx[b] = fin;
        atomicAdd(&cnt[fin], 1);
        atomicMin(&segmin[fin], enc);
        atomicAdd(&zcnt[zb], 1);
    }
}

__global__ __launch_bounds__(256) void wx_out_kernel(
    const float* __restrict__ wxw, const float* __restrict__ inv_wx,
    const float* __restrict__ x, const float* __restrict__ inv_x,
    const int* __restrict__ final_idx, const int* __restrict__ cnt,
    const float* __restrict__ y_age, float* __restrict__ outw) {
    int j = blockIdx.x;
    int t = threadIdx.x;
    __shared__ int s_b[1024];
    __shared__ int s_n;
    if (t == 0) s_n = 0;
    __syncthreads();
    int c = cnt[j];
    if (c > 0) {
        for (int b = t; b < B_N; b += 256)
            if (final_idx[b] == j) { int p = atomicAdd(&s_n, 1); s_b[p] = b; }
    }
    __syncthreads();
    float inv = inv_wx[j];
    float lr = 1.0f / (y_age[j] + 1.0f);
    float fc = (float)c;
    float dv = (c > 0) ? fc : 1.0f;
    int n = s_n;
    float4 w = *reinterpret_cast<const float4*>(wxw + (size_t)j * X_N + t * 4);
    float4 wn = make_float4(w.x*inv, w.y*inv, w.z*inv, w.w*inv);
    if (c > 0) {
        float4 s = make_float4(0.f, 0.f, 0.f, 0.f);
        for (int m = 0; m < n; ++m) {
            int b = s_b[m];
            float ix = inv_x[b];
            float4 xv = *reinterpret_cast<const float4*>(x + (size_t)b * X_N + t * 4);
            s.x += xv.x * ix; s.y += xv.y * ix; s.z += xv.z * ix; s.w += xv.w * ix;
        }
        float f = lr / dv;
        wn.x += f * (s.x - fc * wn.x);
        wn.y += f * (s.y - fc * wn.y);
        wn.z += f * (s.z - fc * wn.z);
        wn.w += f * (s.w - fc * wn.w);
    }
    *reinterpret_cast<float4*>(outw + (size_t)j * X_N + t * 4) = wn;
}

__global__ __launch_bounds__(256) void wz_out_kernel(
    const float* __restrict__ wzw, const float* __restrict__ inv_wz,
    const int* __restrict__ zlab, const int* __restrict__ final_idx,
    const int* __restrict__ cnt, const float* __restrict__ y_age,
    float* __restrict__ outw) {
    int j = blockIdx.x;
    int t = threadIdx.x;
    __shared__ int s_c[1024];
    __shared__ int s_n;
    if (t == 0) s_n = 0;
    __syncthreads();
    int c = cnt[j];
    if (c > 0) {
        for (int b = t; b < B_N; b += 256)
            if (final_idx[b] == j) { int p = atomicAdd(&s_n, 1); s_c[p] = zlab[b]; }
    }
    __syncthreads();
    if (t >= 250) return;
    float inv = inv_wz[j];
    float lr = 1.0f / (y_age[j] + 1.0f);
    float fc = (float)c;
    float dv = (c > 0) ? fc : 1.0f;
    int n = s_n;
    float4 w = *reinterpret_cast<const float4*>(wzw + (size_t)j * Z_N + t * 4);
    float4 wn = make_float4(w.x*inv, w.y*inv, w.z*inv, w.w*inv);
    if (c > 0) {
        float4 s = make_float4(0.f, 0.f, 0.f, 0.f);
        for (int m = 0; m < n; ++m) {
            int d = s_c[m] - t * 4;
            if (d == 0) s.x += 1.f;
            else if (d == 1) s.y += 1.f;
            else if (d == 2) s.z += 1.f;
            else if (d == 3) s.w += 1.f;
        }
        float f = lr / dv;
        wn.x += f * (s.x - fc * wn.x);
        wn.y += f * (s.y - fc * wn.y);
        wn.z += f * (s.z - fc * wn.z);
        wn.w += f * (s.w - fc * wn.w);
    }
    *reinterpret_cast<float4*>(outw + (size_t)j * Z_N + t * 4) = wn;
}

// fused: row-norm of U + U update (row held in registers; one read, one write)
__global__ __launch_bounds__(256) void u_out_kernel(
    const float* __restrict__ uw, const int* __restrict__ zlab,
    const int* __restrict__ final_idx, const int* __restrict__ zcnt,
    const float* __restrict__ z_age, float* __restrict__ outw) {
    int cz = blockIdx.x;
    int t = threadIdx.x;
    const int lane = t & 63, wid = t >> 6;
    __shared__ int s_w[1024];
    __shared__ int s_n;
    __shared__ float rss[4];
    if (t == 0) s_n = 0;

    const float4* rowp4 = reinterpret_cast<const float4*>(uw + (size_t)cz * Y_N);
    float4 u[16];
    float ss = 0.f;
    #pragma unroll
    for (int p = 0; p < 16; ++p) {
        u[p] = rowp4[p * 256 + t];
        ss += u[p].x*u[p].x + u[p].y*u[p].y + u[p].z*u[p].z + u[p].w*u[p].w;
    }
    #pragma unroll
    for (int s = 32; s > 0; s >>= 1) ss += __shfl_xor(ss, s, 64);
    if (lane == 0) rss[wid] = ss;
    __syncthreads();
    float inv = 1.0f / fmaxf(sqrtf(rss[0] + rss[1] + rss[2] + rss[3]), 1e-12f);

    int c = zcnt[cz];
    if (c > 0) {
        for (int b = t; b < B_N; b += 256)
            if (zlab[b] == cz) { int p = atomicAdd(&s_n, 1); s_w[p] = final_idx[b]; }
    }
    __syncthreads();
    float zlr = 1.0f / (z_age[cz] + 1.0f);
    float fc = (float)c;
    float dv = (c > 0) ? fc : 1.0f;
    float f = zlr / dv;
    int n = s_n;
    float* outp = outw + (size_t)cz * Y_N;
    #pragma unroll
    for (int p = 0; p < 16; ++p) {
        int e4 = p * 256 + t;
        float4 un = make_float4(u[p].x*inv, u[p].y*inv, u[p].z*inv, u[p].w*inv);
        if (c > 0) {
            float4 s = make_float4(0.f, 0.f, 0.f, 0.f);
            for (int m = 0; m < n; ++m) {
                int d = s_w[m] - e4 * 4;
                if (d == 0) s.x += 1.f;
                else if (d == 1) s.y += 1.f;
                else if (d == 2) s.z += 1.f;
                else if (d == 3) s.w += 1.f;
            }
            un.x += f * (s.x - fc * un.x);
            un.y += f * (s.y - fc * un.y);
            un.z += f * (s.z - fc * un.z);
            un.w += f * (s.w - fc * un.w);
        }
        *reinterpret_cast<float4*>(outp + e4 * 4) = un;
    }
}

__global__ void thr_age_kernel(const int* __restrict__ cnt, const unsigned* __restrict__ segmin,
                               const float* __restrict__ y_age, const float* __restrict__ y_thr,
                               float* __restrict__ out_thr, float* __restrict__ out_age,
                               int* ctr) {
    int j = blockIdx.x * 256 + threadIdx.x;
    int c = cnt[j];
    float age = y_age[j];
    float thr = y_thr[j];
    float tn = thr;
    if (c > 0) {
        float lr = 1.0f / (age + 1.0f);
        float smin = dec_f(segmin[j]);
        float ycur = fminf(smin, 3.0f);
        if (ycur > 2.0f) ycur = 0.0f;
        tn = lr * ycur + (1.0f - lr) * thr;
    }
    out_thr[j] = tn;
    float an = age + (float)c;
    out_age[j] = an;
    unsigned long long m = __ballot(an >= 1.0f ? 1 : 0);
    if ((threadIdx.x & 63) == 0) atomicAdd(ctr + 1, (int)__popcll(m));
}

__global__ void zage_act_kernel(const int* __restrict__ zcnt, const float* __restrict__ z_age,
                                const int* __restrict__ ctr, float* __restrict__ out_zage,
                                float* __restrict__ out_act) {
    int i = blockIdx.x * 256 + threadIdx.x;
    if (i < Z_N) out_zage[i] = z_age[i] + (float)zcnt[i];
    if (i == 0) out_act[0] = (float)ctr[1];
}

extern "C" void kernel_launch(void* const* d_in, const int* in_sizes, int n_in,
                              void* d_out, int out_size, void* d_ws, size_t ws_size,
                              hipStream_t stream) {
    const float* x     = (const float*)d_in[0];
    const int*   z     = (const int*)d_in[1];
    const float* wxw   = (const float*)d_in[2];
    const float* wzw   = (const float*)d_in[3];
    const float* uw    = (const float*)d_in[4];
    const float* y_age = (const float*)d_in[5];
    const float* z_age = (const float*)d_in[6];
    const float* y_thr = (const float*)d_in[7];
    float* out = (float*)d_out;
    float* ws  = (float*)d_ws;
    char*  ob  = (char*)d_out;

    float* inv_x  = ws + WS_INV_X;
    float* inv_wx = ws + WS_INV_WX;
    float* inv_wz = ws + WS_INV_WZ;
    int* fidx = (int*)(ws + WS_FIDX);
    int* cnt  = (int*)(ws + WS_CNT);
    int* zcnt = (int*)(ws + WS_ZCNT);
    unsigned* segmin = (unsigned*)(ws + WS_SEGMIN);
    int* ctr = (int*)(ws + WS_CTR);
    unsigned long long* mbits = (unsigned long long*)(ws + WS_MBITS);
    int* ccnt = (int*)(ws + WS_CCNT);

    ushort_t* Bb  = (ushort_t*)(ob + SCR_B_BYTES);
    ushort_t* Sc  = (ushort_t*)(ob + SCR_S_BYTES);
    ushort_t* Ab  = (ushort_t*)(ob + SCR_A_BYTES);
    unsigned* gcand = (unsigned*)(ob + SCR_CAND_BYTES);
    ushort_t* wzt = (ushort_t*)(ob + SCR_WZT_BYTES);

    init_kernel<<<64, 256, 0, stream>>>(cnt, segmin, zcnt, ctr);
    unact_kernel<<<Y_N / 256, 256, 0, stream>>>(y_age, ctr, mbits);
    pack_x_kernel<<<B_N, 256, 0, stream>>>(x, Ab, inv_x);
    pack_w_kernel<<<Y_N, 256, 0, stream>>>(wxw, Bb, inv_wx);
    wz_prep_kernel<<<Y_N / 64, 256, 0, stream>>>(wzw, wzt, inv_wz);
    mm256_kernel<<<(B_N / 256) * (Y_N / 256), 512, 0, stream>>>(Ab, Bb, Sc);
    scan_kernel<<<B_N, 256, 0, stream>>>(Sc, wzt, z, mbits, ctr, gcand, ccnt);
    rescore_kernel<<<B_N, 256, 0, stream>>>(gcand, ccnt, x, inv_x, wxw, inv_wx, wzw, inv_wz,
                                            z, y_thr, y_age, ctr, fidx, cnt, segmin, zcnt,
                                            out + OFF_MAXRESP);
    wx_out_kernel<<<Y_N, 256, 0, stream>>>(wxw, inv_wx, x, inv_x, fidx, cnt, y_age, out + OFF_WX);
    wz_out_kernel<<<Y_N, 256, 0, stream>>>(wzw, inv_wz, z, fidx, cnt, y_age, out + OFF_WZ);
    u_out_kernel<<<Z_N, 256, 0, stream>>>(uw, z, fidx, zcnt, z_age, out + OFF_U);
    thr_age_kernel<<<Y_N / 256, 256, 0, stream>>>(cnt, segmin, y_age, y_thr,
                                                  out + OFF_THR, out + OFF_AGE, ctr);
    zage_act_kernel<<<4, 256, 0, stream>>>(zcnt, z_age, ctr, out + OFF_ZAGE, out + OFF_ACT);
}

// Round 11
// 235.571 us; speedup vs baseline: 1.1783x; 1.1783x over previous
//
#include <hip/hip_runtime.h>

#define B_N 1024
#define X_N 1024
#define Y_N 16384
#define Z_N 1000
#define KD  1024
#define MARGIN 0.004f

// output float offsets
#define OFF_ACT      0
#define OFF_MAXRESP  1
#define OFF_WX       1025
#define OFF_WZ       16778241
#define OFF_U        33162241
#define OFF_THR      49546241
#define OFF_AGE      49562625
#define OFF_ZAGE     49579009

// scratch in not-yet-written d_out regions (16B-aligned byte offsets)
#define SCR_B_BYTES    4112ull       /* Bb f16 32MB, in OFF_WX region */
#define SCR_S_BYTES    67112976ull   /* Sc f16 32MB, in OFF_WZ region */
#define SCR_A_BYTES    132648976ull  /* Ab f16 2MB, in OFF_U region */
#define SCR_WZT_BYTES  136843280ull  /* wzt f16 [1024 z-slots][Y_N] 32MB, in OFF_U region */

// ws float offsets
#define WS_INV_X    0
#define WS_INV_WX   1024
#define WS_INV_WZ   17408
#define WS_FIDX     38912   /* int[1024] */
#define WS_CNT      39936   /* int[16384] */
#define WS_ZCNT     56320   /* int[1024] */
#define WS_SEGMIN   57344   /* uint[16384] */
#define WS_CTR      73728   /* int[8]: [0]=unact_cnt [1]=act_cnt [2]=min_act_idx */
#define WS_MBITS    73736   /* u64[256] */

typedef unsigned short ushort_t;
typedef _Float16 f16x8 __attribute__((ext_vector_type(8)));
typedef float f32x4 __attribute__((ext_vector_type(4)));

__device__ __forceinline__ unsigned enc_f(float f) {
    unsigned u = __float_as_uint(f);
    return (u & 0x80000000u) ? ~u : (u | 0x80000000u);
}
__device__ __forceinline__ float dec_f(unsigned e) {
    unsigned u = (e & 0x80000000u) ? (e ^ 0x80000000u) : ~e;
    return __uint_as_float(u);
}
__device__ __forceinline__ unsigned long long pack_vi(float v, int y) {
    return ((unsigned long long)enc_f(v) << 32) |
           (unsigned long long)(0xFFFFFFFFu - (unsigned)y);
}
__device__ __forceinline__ ushort_t f2h(float f) {
    _Float16 h = (_Float16)f;           // RTNE
    ushort_t u; __builtin_memcpy(&u, &h, 2); return u;
}
__device__ __forceinline__ float h2f(unsigned lo16) {
    ushort_t u = (ushort_t)lo16; _Float16 h;
    __builtin_memcpy(&h, &u, 2); return (float)h;
}

#define GLOAD16(gp, lp) __builtin_amdgcn_global_load_lds( \
    (const __attribute__((address_space(1))) void*)(gp),  \
    (__attribute__((address_space(3))) void*)(lp), 16, 0, 0)

__global__ void init_kernel(int* cnt, unsigned* segmin, int* zcnt, int* ctr) {
    int i = blockIdx.x * 256 + threadIdx.x;
    if (i < Y_N) { cnt[i] = 0; segmin[i] = 0xFFFFFFFFu; }
    if (i < 1024) zcnt[i] = 0;
    if (i < 8) ctr[i] = (i == 2) ? 0x7FFFFFFF : 0;
}

// role-merged: unact (64 blocks) | pack_x (B_N) | pack_w (Y_N)
__global__ __launch_bounds__(256) void prep_kernel(
    const float* __restrict__ y_age, int* ctr, unsigned long long* __restrict__ mbits,
    const float* __restrict__ x, ushort_t* __restrict__ A, float* __restrict__ inv_x,
    const float* __restrict__ wxw, const float* __restrict__ wzw,
    ushort_t* __restrict__ Bm, float* __restrict__ inv_wx, float* __restrict__ inv_wz) {
    const int bid = blockIdx.x, t = threadIdx.x;
    const int lane = t & 63, wid = t >> 6;
    __shared__ float red1[4], red2[4];

    if (bid < 64) {
        // ---- unact ----
        int i = bid * 256 + t;
        int a = (y_age[i] < 1.0f) ? 1 : 0;
        unsigned long long m = __ballot(a);
        int mi = a ? 0x7FFFFFFF : i;   // min index over ACTIVATED neurons
        #pragma unroll
        for (int s = 32; s > 0; s >>= 1) mi = min(mi, __shfl_xor(mi, s, 64));
        if (lane == 0) {
            atomicAdd(ctr, (int)__popcll(m));
            mbits[i >> 6] = m;
            if (mi != 0x7FFFFFFF) atomicMin(&ctr[2], mi);
        }
    } else if (bid < 64 + B_N) {
        // ---- pack_x: row-norm of x + A row [b][KD] f16 = x_hat ----
        int b = bid - 64;
        float4 v = reinterpret_cast<const float4*>(x + (size_t)b * X_N)[t];
        float ss = v.x*v.x + v.y*v.y + v.z*v.z + v.w*v.w;
        #pragma unroll
        for (int s = 32; s > 0; s >>= 1) ss += __shfl_xor(ss, s, 64);
        if (lane == 0) red1[wid] = ss;
        __syncthreads();
        float inv = 1.0f / fmaxf(sqrtf(red1[0] + red1[1] + red1[2] + red1[3]), 1e-12f);
        if (t == 0) inv_x[b] = inv;
        ushort_t o1[4] = { f2h(v.x*inv), f2h(v.y*inv), f2h(v.z*inv), f2h(v.w*inv) };
        *reinterpret_cast<uint2*>(A + (size_t)b * KD + t * 4) = *reinterpret_cast<uint2*>(o1);
    } else {
        // ---- pack_w: row-norms of wxw/wzw + B row [y][KD] f16 = wx_hat ----
        int y = bid - 64 - B_N;
        float4 a = reinterpret_cast<const float4*>(wxw + (size_t)y * X_N)[t];
        float4 zv = make_float4(0.f, 0.f, 0.f, 0.f);
        if (t < 250) zv = reinterpret_cast<const float4*>(wzw + (size_t)y * Z_N)[t];
        float s1 = a.x*a.x + a.y*a.y + a.z*a.z + a.w*a.w;
        float s2 = zv.x*zv.x + zv.y*zv.y + zv.z*zv.z + zv.w*zv.w;
        #pragma unroll
        for (int s = 32; s > 0; s >>= 1) {
            s1 += __shfl_xor(s1, s, 64);
            s2 += __shfl_xor(s2, s, 64);
        }
        if (lane == 0) { red1[wid] = s1; red2[wid] = s2; }
        __syncthreads();
        float inv1 = 1.0f / fmaxf(sqrtf(red1[0] + red1[1] + red1[2] + red1[3]), 1e-12f);
        float inv2 = 1.0f / fmaxf(sqrtf(red2[0] + red2[1] + red2[2] + red2[3]), 1e-12f);
        ushort_t o1[4] = { f2h(a.x*inv1), f2h(a.y*inv1), f2h(a.z*inv1), f2h(a.w*inv1) };
        *reinterpret_cast<uint2*>(Bm + (size_t)y * KD + t * 4) = *reinterpret_cast<uint2*>(o1);
        if (t == 0) { inv_wx[y] = inv1; inv_wz[y] = inv2; }
    }
}

// LDS-tiled transpose: wzt[z][y] = 0.5 * wzw[y][z] * inv_wz[y]  (f16)
// block = 64z x 64y tile; grid = 16 z-tiles x 256 y-tiles  (needs inv_wz -> after prep)
__global__ __launch_bounds__(256) void wzt_kernel(
    const float* __restrict__ wzw, const float* __restrict__ inv_wz,
    ushort_t* __restrict__ wzt) {
    const int bid = blockIdx.x;
    const int z0 = (bid & 15) * 64, y0 = (bid >> 4) * 64;
    const int t = threadIdx.x;
    __shared__ float tile[64][65];
    #pragma unroll
    for (int p = 0; p < 4; ++p) {
        int yr = p * 16 + (t >> 4);
        int z = z0 + (t & 15) * 4;
        float4 v = make_float4(0.f, 0.f, 0.f, 0.f);
        if (z + 3 < Z_N)
            v = *reinterpret_cast<const float4*>(wzw + (size_t)(y0 + yr) * Z_N + z);
        float s = 0.5f * inv_wz[y0 + yr];
        tile[(t & 15) * 4 + 0][yr] = v.x * s;
        tile[(t & 15) * 4 + 1][yr] = v.y * s;
        tile[(t & 15) * 4 + 2][yr] = v.z * s;
        tile[(t & 15) * 4 + 3][yr] = v.w * s;
    }
    __syncthreads();
    #pragma unroll
    for (int p = 0; p < 4; ++p) {
        int zr = p * 16 + (t >> 4);
        int yc = (t & 15) * 4;
        if (z0 + zr < 1024) {
            ushort_t o[4] = { f2h(tile[zr][yc]), f2h(tile[zr][yc + 1]),
                              f2h(tile[zr][yc + 2]), f2h(tile[zr][yc + 3]) };
            *reinterpret_cast<uint2*>(wzt + (size_t)(z0 + zr) * Y_N + y0 + yc) =
                *reinterpret_cast<uint2*>(o);
        }
    }
}

// f16 MFMA GEMM, 256x256 tile, K=1024, BK=32, 4-buffer 3-deep counted-vmcnt pipeline
__global__ __launch_bounds__(512, 1) void mm256_kernel(const ushort_t* __restrict__ A,
                                                       const ushort_t* __restrict__ Bm,
                                                       ushort_t* __restrict__ S) {
    __shared__ __align__(16) _Float16 lds[4][2][1024][8];
    const int t = threadIdx.x;
    const int wid = t >> 6, lane = t & 63;
    const int bid = blockIdx.x;
    const int lb = (bid & 7) * 32 + (bid >> 3);   // bijective: 256 % 8 == 0
    const int mt = lb & 3, nt = lb >> 2;
    const int b0 = mt * 256, y0 = nt * 256;
    const int wr = wid >> 2, wc = wid & 3;        // 2 x 4 waves
    const int r = lane & 15, gq = lane >> 4;
    const int NK = KD / 32;                        // 32 K-tiles

    f32x4 acc[8][4];
    #pragma unroll
    for (int i = 0; i < 8; ++i)
        #pragma unroll
        for (int j = 0; j < 4; ++j) acc[i][j] = (f32x4){0.f, 0.f, 0.f, 0.f};

    auto stage = [&](int buf, int k0) {
        #pragma unroll
        for (int rr = 0; rr < 2; ++rr) {
            int s = rr * 512 + t;
            int row = s & 255, g = s >> 8;     // g in [0,4)
            GLOAD16(A  + (size_t)(b0 + row) * KD + k0 + g * 8, &lds[buf][0][s][0]);
            GLOAD16(Bm + (size_t)(y0 + row) * KD + k0 + g * 8, &lds[buf][1][s][0]);
        }
    };

    stage(0, 0);
    stage(1, 32);
    stage(2, 64);
    asm volatile("s_waitcnt vmcnt(8)" ::: "memory");
    __builtin_amdgcn_s_barrier();
    asm volatile("" ::: "memory");

    for (int ks = 0; ks < NK; ++ks) {
        const int cur = ks & 3;
        f16x8 bF[4];
        #pragma unroll
        for (int nf = 0; nf < 4; ++nf)
            bF[nf] = *reinterpret_cast<const f16x8*>(
                &lds[cur][1][gq * 256 + wc * 64 + nf * 16 + r][0]);
        __builtin_amdgcn_s_setprio(1);
        #pragma unroll
        for (int mf = 0; mf < 8; ++mf) {
            f16x8 aF = *reinterpret_cast<const f16x8*>(
                &lds[cur][0][gq * 256 + wr * 128 + mf * 16 + r][0]);
            #pragma unroll
            for (int nf = 0; nf < 4; ++nf)
                acc[mf][nf] = __builtin_amdgcn_mfma_f32_16x16x32_f16(
                    aF, bF[nf], acc[mf][nf], 0, 0, 0);
        }
        __builtin_amdgcn_s_setprio(0);
        if (ks == NK - 1) break;

        __builtin_amdgcn_s_barrier();            // all waves done reading buf[cur]
        asm volatile("" ::: "memory");
        if (ks + 3 < NK) {
            stage((ks + 3) & 3, (ks + 3) * 32);
            asm volatile("s_waitcnt vmcnt(8)" ::: "memory");  // tile ks+1 landed
        } else if (ks + 3 == NK) {
            asm volatile("s_waitcnt vmcnt(4)" ::: "memory");
        } else {
            asm volatile("s_waitcnt vmcnt(0)" ::: "memory");
        }
        __builtin_amdgcn_s_barrier();
        asm volatile("" ::: "memory");
    }

    // C layout: col = lane&15, row = (lane>>4)*4 + reg; store 0.5*dot (x-part)
    #pragma unroll
    for (int mf = 0; mf < 8; ++mf) {
        int bg = b0 + wr * 128 + mf * 16 + gq * 4;
        #pragma unroll
        for (int nf = 0; nf < 4; ++nf) {
            int yg = y0 + wc * 64 + nf * 16 + r;
            f32x4 c = acc[mf][nf];
            #pragma unroll
            for (int q = 0; q < 4; ++q)
                S[(size_t)(bg + q) * Y_N + yg] = f2h(0.5f * c[q]);
        }
    }
}

// fused per-row: scan (max + candidate lists in LDS) + exact fp32 rescore + finalize
__global__ __launch_bounds__(256) void scanres_kernel(
    const ushort_t* __restrict__ scores, const ushort_t* __restrict__ wzt,
    const int* __restrict__ zlab, const unsigned long long* __restrict__ mbits,
    const int* __restrict__ ctr,
    const float* __restrict__ x, const float* __restrict__ inv_x,
    const float* __restrict__ wxw, const float* __restrict__ inv_wx,
    const float* __restrict__ wzw, const float* __restrict__ inv_wz,
    const float* __restrict__ y_thr, const float* __restrict__ y_age,
    int* final_idx, int* cnt, unsigned* segmin, int* zcnt,
    float* __restrict__ out_maxresp) {
    const int b = blockIdx.x, t = threadIdx.x;
    const int lane = t & 63, wid = t >> 6;
    const int zb = zlab[b];
    const uint4* srow = reinterpret_cast<const uint4*>(scores + (size_t)b * Y_N);
    const uint4* wrow = reinterpret_cast<const uint4*>(wzt + (size_t)zb * Y_N);

    __shared__ float rv[4], rm[4];
    __shared__ int nA_s, nB_s;
    __shared__ int cA[256], cB[256];
    __shared__ unsigned long long red[4];
    __shared__ unsigned long long sPM;
    __shared__ int sTakeA;

    // ---- pass 1: approx maxes ----
    float vmax = -1e30f, mmax = -1e30f;
    for (int c = t; c < Y_N / 8; c += 256) {
        uint4 pk = srow[c];
        uint4 wz = wrow[c];
        int yb = c * 8;
        unsigned m8 = (unsigned)((mbits[yb >> 6] >> (yb & 63)) & 0xFFull);
        unsigned w[4] = {pk.x, pk.y, pk.z, pk.w};
        unsigned q[4] = {wz.x, wz.y, wz.z, wz.w};
        #pragma unroll
        for (int j = 0; j < 4; ++j) {
            float v0 = h2f(w[j] & 0xFFFFu) + h2f(q[j] & 0xFFFFu);
            float v1 = h2f(w[j] >> 16) + h2f(q[j] >> 16);
            vmax = fmaxf(vmax, fmaxf(v0, v1));
            mmax = fmaxf(mmax, v0 * (float)((m8 >> (2 * j)) & 1u));
            mmax = fmaxf(mmax, v1 * (float)((m8 >> (2 * j + 1)) & 1u));
        }
    }
    #pragma unroll
    for (int s = 32; s > 0; s >>= 1) {
        vmax = fmaxf(vmax, __shfl_xor(vmax, s, 64));
        mmax = fmaxf(mmax, __shfl_xor(mmax, s, 64));
    }
    if (lane == 0) { rv[wid] = vmax; rm[wid] = mmax; }
    if (t == 0) { nA_s = 0; nB_s = 0; }
    __syncthreads();
    float tA = fmaxf(fmaxf(rv[0], rv[1]), fmaxf(rv[2], rv[3])) - MARGIN;
    float tB = fmaxf(fmaxf(rm[0], rm[1]), fmaxf(rm[2], rm[3])) - MARGIN;
    bool anyu = ctr[0] > 0;

    // ---- pass 2: candidate collection (LDS lists only) ----
    for (int c = t; c < Y_N / 8; c += 256) {
        uint4 pk = srow[c];
        uint4 wz = wrow[c];
        int yb = c * 8;
        unsigned m8 = (unsigned)((mbits[yb >> 6] >> (yb & 63)) & 0xFFull);
        unsigned w[4] = {pk.x, pk.y, pk.z, pk.w};
        unsigned q[4] = {wz.x, wz.y, wz.z, wz.w};
        #pragma unroll
        for (int j = 0; j < 8; ++j) {
            unsigned sw = (j & 1) ? (w[j >> 1] >> 16) : (w[j >> 1] & 0xFFFFu);
            unsigned qw = (j & 1) ? (q[j >> 1] >> 16) : (q[j >> 1] & 0xFFFFu);
            float v = h2f(sw) + h2f(qw);
            if (v >= tA) { int p = atomicAdd(&nA_s, 1); if (p < 256) cA[p] = yb + j; }
            if (anyu && ((m8 >> j) & 1u) && v >= tB) {
                int p = atomicAdd(&nB_s, 1); if (p < 256) cB[p] = yb + j;
            }
        }
    }
    __syncthreads();
    int nA = min(nA_s, 256), nB = min(nB_s, 256);

    // ---- exact fp32 rescore: list A ----
    float invx = inv_x[b];
    const float4* xr = reinterpret_cast<const float4*>(x + (size_t)b * X_N);
    float4 xv[4];
    #pragma unroll
    for (int j = 0; j < 4; ++j) xv[j] = xr[j * 64 + lane];

    unsigned long long bA = 0ull;
    for (int c = wid; c < nA; c += 8) {
        int y1 = cA[c];
        int c2 = c + 4;
        bool h2 = c2 < nA;
        int y2 = cA[h2 ? c2 : c];
        const float4* w1 = reinterpret_cast<const float4*>(wxw + (size_t)y1 * X_N);
        const float4* w2 = reinterpret_cast<const float4*>(wxw + (size_t)y2 * X_N);
        float d1 = 0.f, d2 = 0.f;
        #pragma unroll
        for (int j = 0; j < 4; ++j) {
            float4 a1 = w1[j * 64 + lane];
            float4 a2 = w2[j * 64 + lane];
            d1 += xv[j].x*a1.x + xv[j].y*a1.y + xv[j].z*a1.z + xv[j].w*a1.w;
            d2 += xv[j].x*a2.x + xv[j].y*a2.y + xv[j].z*a2.z + xv[j].w*a2.w;
        }
        #pragma unroll
        for (int s = 32; s > 0; s >>= 1) {
            d1 += __shfl_xor(d1, s, 64);
            d2 += __shfl_xor(d2, s, 64);
        }
        float v1 = 0.5f*invx*inv_wx[y1]*d1 + 0.5f*inv_wz[y1]*wzw[(size_t)y1*Z_N + zb];
        unsigned long long p1 = pack_vi(v1, y1);
        bA = (p1 > bA) ? p1 : bA;
        if (h2) {
            float v2 = 0.5f*invx*inv_wx[y2]*d2 + 0.5f*inv_wz[y2]*wzw[(size_t)y2*Z_N + zb];
            unsigned long long p2 = pack_vi(v2, y2);
            bA = (p2 > bA) ? p2 : bA;
        }
    }
    if (lane == 0) red[wid] = bA;
    __syncthreads();
    if (t == 0) {
        unsigned long long pm = red[0];
        #pragma unroll
        for (int j = 1; j < 4; ++j) pm = (red[j] > pm) ? red[j] : pm;
        sPM = pm;
        unsigned enc = (unsigned)(pm >> 32);
        int idx = (int)(0xFFFFFFFFu - (unsigned)(pm & 0xFFFFFFFFull));
        float mresp = dec_f(enc);
        out_maxresp[b] = mresp;
        bool judge = (mresp > y_thr[idx]) || (y_age[idx] < 1.0f);
        sTakeA = (judge || !anyu) ? 1 : 0;
    }
    __syncthreads();

    // ---- list B only when fallback needed ----
    if (!sTakeA) {
        unsigned long long bB = 0ull;
        for (int c = wid; c < nB; c += 8) {
            int y1 = cB[c];
            int c2 = c + 4;
            bool h2 = c2 < nB;
            int y2 = cB[h2 ? c2 : c];
            const float4* w1 = reinterpret_cast<const float4*>(wxw + (size_t)y1 * X_N);
            const float4* w2 = reinterpret_cast<const float4*>(wxw + (size_t)y2 * X_N);
            float d1 = 0.f, d2 = 0.f;
            #pragma unroll
            for (int j = 0; j < 4; ++j) {
                float4 a1 = w1[j * 64 + lane];
                float4 a2 = w2[j * 64 + lane];
                d1 += xv[j].x*a1.x + xv[j].y*a1.y + xv[j].z*a1.z + xv[j].w*a1.w;
                d2 += xv[j].x*a2.x + xv[j].y*a2.y + xv[j].z*a2.z + xv[j].w*a2.w;
            }
            #pragma unroll
            for (int s = 32; s > 0; s >>= 1) {
                d1 += __shfl_xor(d1, s, 64);
                d2 += __shfl_xor(d2, s, 64);
            }
            float v1 = 0.5f*invx*inv_wx[y1]*d1 + 0.5f*inv_wz[y1]*wzw[(size_t)y1*Z_N + zb];
            unsigned long long p1 = pack_vi(v1, y1);
            bB = (p1 > bB) ? p1 : bB;
            if (h2) {
                float v2 = 0.5f*invx*inv_wx[y2]*d2 + 0.5f*inv_wz[y2]*wzw[(size_t)y2*Z_N + zb];
                unsigned long long p2 = pack_vi(v2, y2);
                bB = (p2 > bB) ? p2 : bB;
            }
        }
        if (lane == 0) red[wid] = bB;
    }
    __syncthreads();
    if (t == 0) {
        unsigned long long pm = sPM;
        unsigned enc = (unsigned)(pm >> 32);
        int idx = (int)(0xFFFFFFFFu - (unsigned)(pm & 0xFFFFFFFFull));
        int fin;
        if (sTakeA) {
            fin = idx;
        } else if (nB > 0) {
            unsigned long long pf = red[0];
            #pragma unroll
            for (int j = 1; j < 4; ++j) pf = (red[j] > pf) ? red[j] : pf;
            fin = (int)(0xFFFFFFFFu - (unsigned)(pf & 0xFFFFFFFFull));
        } else {
            fin = ctr[2];   // all-unact-nonpositive: ref argmax lands on first activated
        }
        final_idx[b] = fin;
        atomicAdd(&cnt[fin], 1);
        atomicMin(&segmin[fin], enc);
        atomicAdd(&zcnt[zb], 1);
    }
}

// role-merged outputs: u_out (Z_N) | wx_out (Y_N) | wz_out (Y_N) | thr_age (64) | zage (4)
__global__ __launch_bounds__(256) void out_kernel(
    const float* __restrict__ wxw, const float* __restrict__ inv_wx,
    const float* __restrict__ x, const float* __restrict__ inv_x,
    const float* __restrict__ wzw, const float* __restrict__ inv_wz,
    const float* __restrict__ uw, const int* __restrict__ zlab,
    const int* __restrict__ final_idx, const int* __restrict__ cnt,
    const int* __restrict__ zcnt, const unsigned* __restrict__ segmin,
    const float* __restrict__ y_age, const float* __restrict__ z_age,
    const float* __restrict__ y_thr, float* __restrict__ out, int* ctr) {
    const int bid = blockIdx.x, t = threadIdx.x;
    const int lane = t & 63, wid = t >> 6;
    __shared__ int s_idx[1024];
    __shared__ int s_n;
    __shared__ float rss[4];

    if (bid < Z_N) {
        // ---- u_out: row-norm of U + update, row in registers ----
        int cz = bid;
        if (t == 0) s_n = 0;
        const float4* rowp4 = reinterpret_cast<const float4*>(uw + (size_t)cz * Y_N);
        float4 u[16];
        float ss = 0.f;
        #pragma unroll
        for (int p = 0; p < 16; ++p) {
            u[p] = rowp4[p * 256 + t];
            ss += u[p].x*u[p].x + u[p].y*u[p].y + u[p].z*u[p].z + u[p].w*u[p].w;
        }
        #pragma unroll
        for (int s = 32; s > 0; s >>= 1) ss += __shfl_xor(ss, s, 64);
        if (lane == 0) rss[wid] = ss;
        __syncthreads();
        float inv = 1.0f / fmaxf(sqrtf(rss[0] + rss[1] + rss[2] + rss[3]), 1e-12f);
        int c = zcnt[cz];
        if (c > 0) {
            for (int b = t; b < B_N; b += 256)
                if (zlab[b] == cz) { int p = atomicAdd(&s_n, 1); s_idx[p] = final_idx[b]; }
        }
        __syncthreads();
        float zlr = 1.0f / (z_age[cz] + 1.0f);
        float fc = (float)c;
        float dv = (c > 0) ? fc : 1.0f;
        float f = zlr / dv;
        int n = s_n;
        float* outp = out + OFF_U + (size_t)cz * Y_N;
        #pragma unroll
        for (int p = 0; p < 16; ++p) {
            int e4 = p * 256 + t;
            float4 un = make_float4(u[p].x*inv, u[p].y*inv, u[p].z*inv, u[p].w*inv);
            if (c > 0) {
                float4 s = make_float4(0.f, 0.f, 0.f, 0.f);
                for (int m = 0; m < n; ++m) {
                    int d = s_idx[m] - e4 * 4;
                    if (d == 0) s.x += 1.f;
                    else if (d == 1) s.y += 1.f;
                    else if (d == 2) s.z += 1.f;
                    else if (d == 3) s.w += 1.f;
                }
                un.x += f * (s.x - fc * un.x);
                un.y += f * (s.y - fc * un.y);
                un.z += f * (s.z - fc * un.z);
                un.w += f * (s.w - fc * un.w);
            }
            *reinterpret_cast<float4*>(outp + e4 * 4) = un;
        }
    } else if (bid < Z_N + Y_N) {
        // ---- wx_out ----
        int j = bid - Z_N;
        if (t == 0) s_n = 0;
        __syncthreads();
        int c = cnt[j];
        if (c > 0) {
            for (int b = t; b < B_N; b += 256)
                if (final_idx[b] == j) { int p = atomicAdd(&s_n, 1); s_idx[p] = b; }
        }
        __syncthreads();
        float inv = inv_wx[j];
        float lr = 1.0f / (y_age[j] + 1.0f);
        float fc = (float)c;
        float dv = (c > 0) ? fc : 1.0f;
        int n = s_n;
        float4 w = *reinterpret_cast<const float4*>(wxw + (size_t)j * X_N + t * 4);
        float4 wn = make_float4(w.x*inv, w.y*inv, w.z*inv, w.w*inv);
        if (c > 0) {
            float4 s = make_float4(0.f, 0.f, 0.f, 0.f);
            for (int m = 0; m < n; ++m) {
                int b = s_idx[m];
                float ix = inv_x[b];
                float4 xv = *reinterpret_cast<const float4*>(x + (size_t)b * X_N + t * 4);
                s.x += xv.x * ix; s.y += xv.y * ix; s.z += xv.z * ix; s.w += xv.w * ix;
            }
            float f = lr / dv;
            wn.x += f * (s.x - fc * wn.x);
            wn.y += f * (s.y - fc * wn.y);
            wn.z += f * (s.z - fc * wn.z);
            wn.w += f * (s.w - fc * wn.w);
        }
        *reinterpret_cast<float4*>(out + OFF_WX + (size_t)j * X_N + t * 4) = wn;
    } else if (bid < Z_N + 2 * Y_N) {
        // ---- wz_out ----
        int j = bid - Z_N - Y_N;
        if (t == 0) s_n = 0;
        __syncthreads();
        int c = cnt[j];
        if (c > 0) {
            for (int b = t; b < B_N; b += 256)
                if (final_idx[b] == j) { int p = atomicAdd(&s_n, 1); s_idx[p] = zlab[b]; }
        }
        __syncthreads();
        if (t >= 250) return;
        float inv = inv_wz[j];
        float lr = 1.0f / (y_age[j] + 1.0f);
        float fc = (float)c;
        float dv = (c > 0) ? fc : 1.0f;
        int n = s_n;
        float4 w = *reinterpret_cast<const float4*>(wzw + (size_t)j * Z_N + t * 4);
        float4 wn = make_float4(w.x*inv, w.y*inv, w.z*inv, w.w*inv);
        if (c > 0) {
            float4 s = make_float4(0.f, 0.f, 0.f, 0.f);
            for (int m = 0; m < n; ++m) {
                int d = s_idx[m] - t * 4;
                if (d == 0) s.x += 1.f;
                else if (d == 1) s.y += 1.f;
                else if (d == 2) s.z += 1.f;
                else if (d == 3) s.w += 1.f;
            }
            float f = lr / dv;
            wn.x += f * (s.x - fc * wn.x);
            wn.y += f * (s.y - fc * wn.y);
            wn.z += f * (s.z - fc * wn.z);
            wn.w += f * (s.w - fc * wn.w);
        }
        *reinterpret_cast<float4*>(out + OFF_WZ + (size_t)j * Z_N + t * 4) = wn;
    } else if (bid < Z_N + 2 * Y_N + 64) {
        // ---- thr_age ----
        int j = (bid - Z_N - 2 * Y_N) * 256 + t;
        int c = cnt[j];
        float age = y_age[j];
        float thr = y_thr[j];
        float tn = thr;
        if (c > 0) {
            float lr = 1.0f / (age + 1.0f);
            float smin = dec_f(segmin[j]);
            float ycur = fminf(smin, 3.0f);
            if (ycur > 2.0f) ycur = 0.0f;
            tn = lr * ycur + (1.0f - lr) * thr;
        }
        out[OFF_THR + j] = tn;
        float an = age + (float)c;
        out[OFF_AGE + j] = an;
        unsigned long long m = __ballot(an >= 1.0f ? 1 : 0);
        if (lane == 0) atomicAdd(ctr + 1, (int)__popcll(m));
    } else {
        // ---- zage ----
        int i = (bid - Z_N - 2 * Y_N - 64) * 256 + t;
        if (i < Z_N) out[OFF_ZAGE + i] = z_age[i] + (float)zcnt[i];
    }
}

__global__ void act_kernel(const int* __restrict__ ctr, float* __restrict__ out_act) {
    if (threadIdx.x == 0) out_act[0] = (float)ctr[1];
}

extern "C" void kernel_launch(void* const* d_in, const int* in_sizes, int n_in,
                              void* d_out, int out_size, void* d_ws, size_t ws_size,
                              hipStream_t stream) {
    const float* x     = (const float*)d_in[0];
    const int*   z     = (const int*)d_in[1];
    const float* wxw   = (const float*)d_in[2];
    const float* wzw   = (const float*)d_in[3];
    const float* uw    = (const float*)d_in[4];
    const float* y_age = (const float*)d_in[5];
    const float* z_age = (const float*)d_in[6];
    const float* y_thr = (const float*)d_in[7];
    float* out = (float*)d_out;
    float* ws  = (float*)d_ws;
    char*  ob  = (char*)d_out;

    float* inv_x  = ws + WS_INV_X;
    float* inv_wx = ws + WS_INV_WX;
    float* inv_wz = ws + WS_INV_WZ;
    int* fidx = (int*)(ws + WS_FIDX);
    int* cnt  = (int*)(ws + WS_CNT);
    int* zcnt = (int*)(ws + WS_ZCNT);
    unsigned* segmin = (unsigned*)(ws + WS_SEGMIN);
    int* ctr = (int*)(ws + WS_CTR);
    unsigned long long* mbits = (unsigned long long*)(ws + WS_MBITS);

    ushort_t* Bb  = (ushort_t*)(ob + SCR_B_BYTES);
    ushort_t* Sc  = (ushort_t*)(ob + SCR_S_BYTES);
    ushort_t* Ab  = (ushort_t*)(ob + SCR_A_BYTES);
    ushort_t* wzt = (ushort_t*)(ob + SCR_WZT_BYTES);

    init_kernel<<<64, 256, 0, stream>>>(cnt, segmin, zcnt, ctr);
    prep_kernel<<<64 + B_N + Y_N, 256, 0, stream>>>(y_age, ctr, mbits, x, Ab, inv_x,
                                                    wxw, wzw, Bb, inv_wx, inv_wz);
    wzt_kernel<<<16 * 256, 256, 0, stream>>>(wzw, inv_wz, wzt);
    mm256_kernel<<<(B_N / 256) * (Y_N / 256), 512, 0, stream>>>(Ab, Bb, Sc);
    scanres_kernel<<<B_N, 256, 0, stream>>>(Sc, wzt, z, mbits, ctr, x, inv_x,
                                            wxw, inv_wx, wzw, inv_wz, y_thr, y_age,
                                            fidx, cnt, segmin, zcnt, out + OFF_MAXRESP);
    out_kernel<<<Z_N + 2 * Y_N + 64 + 4, 256, 0, stream>>>(
        wxw, inv_wx, x, inv_x, wzw, inv_wz, uw, z, fidx, cnt, zcnt, segmin,
        y_age, z_age, y_thr, out, ctr);
    act_kernel<<<1, 64, 0, stream>>>(ctr, out + OFF_ACT);
}